// Round 7
// baseline (1567.291 us; speedup 1.0000x reference)
//
#include <hip/hip_runtime.h>
#include <math.h>

typedef __bf16 bf16_t;
typedef __bf16 bf8v __attribute__((ext_vector_type(8)));
typedef __bf16 bf4v __attribute__((ext_vector_type(4)));
typedef float  f4v  __attribute__((ext_vector_type(4)));

#define BB  8
#define CC  512
#define NN  4096
#define CPG 16
#define NCb (NN * CC)
#define WSZ (CC * CC)

#define FLG_SIZES 805306368.f
#define FLG_WS    536870912.f

__global__ void diag_out(float* out, float v) { if (threadIdx.x == 0) out[0] = v; }

// ---------------------------------------------------------------------------
// Convert the four 512x512 fp32 weights to bf16, packed [Wq|Wk|Wv|Wo].
// ---------------------------------------------------------------------------
__global__ __launch_bounds__(256) void cvt_w(const float* __restrict__ a,
                                             const float* __restrict__ b,
                                             const float* __restrict__ c,
                                             const float* __restrict__ d,
                                             bf16_t* __restrict__ o)
{
    const int i = (blockIdx.x * 256 + threadIdx.x) * 4;
    const float* srcs[4] = {a, b, c, d};
#pragma unroll
    for (int m = 0; m < 4; m++) {
        float4 v = *(const float4*)(srcs[m] + i);
        bf4v w;
        w[0] = (bf16_t)v.x; w[1] = (bf16_t)v.y;
        w[2] = (bf16_t)v.z; w[3] = (bf16_t)v.w;
        *(bf4v*)(o + (size_t)m * WSZ + i) = w;
    }
}

// ---------------------------------------------------------------------------
// GroupNorm stats in fp64 (all batches). stats[bg*2]=mean, [bg*2+1]=rstd.
// ---------------------------------------------------------------------------
__global__ __launch_bounds__(256) void gn_stats(const float* __restrict__ x,
                                                float* __restrict__ stats)
{
    const int bg = blockIdx.x;
    const float* xp = x + (size_t)bg * CPG * NN;
    const int tid = threadIdx.x;
    double s = 0.0, ss = 0.0;
    const float4* xv = (const float4*)xp;
    for (int i = tid; i < (CPG * NN) / 4; i += 256) {
        float4 v = xv[i];
        s  += (double)v.x + (double)v.y + (double)v.z + (double)v.w;
        ss += (double)v.x * v.x + (double)v.y * v.y
            + (double)v.z * v.z + (double)v.w * v.w;
    }
    __shared__ double l1[256], l2[256];
    l1[tid] = s; l2[tid] = ss;
    __syncthreads();
    for (int o = 128; o > 0; o >>= 1) {
        if (tid < o) { l1[tid] += l1[tid + o]; l2[tid] += l2[tid + o]; }
        __syncthreads();
    }
    if (tid == 0) {
        double mean = l1[0] * (1.0 / 65536.0);
        double var  = l2[0] * (1.0 / 65536.0) - mean * mean;
        stats[bg * 2]     = (float)mean;
        stats[bg * 2 + 1] = (float)(1.0 / sqrt(var + 1e-6));
    }
}

// ---------------------------------------------------------------------------
// GN apply for one batch: x_b (C,N) fp32 -> h (N,C) bf16.
// ---------------------------------------------------------------------------
__global__ __launch_bounds__(256) void gn_apply(const float* __restrict__ xb,
                                                const float* __restrict__ gw,
                                                const float* __restrict__ gb,
                                                const float* __restrict__ stats,
                                                bf16_t* __restrict__ h,
                                                int bg0)
{
    const int g  = blockIdx.x >> 3;
    const int sl = blockIdx.x & 7;
    const float* xp = xb + (size_t)g * CPG * NN;
    const int tid = threadIdx.x;
    const float mean = stats[(bg0 + g) * 2];
    const float rstd = stats[(bg0 + g) * 2 + 1];
    const int cw = tid & 15;
    const float aa = rstd * gw[g * CPG + cw];
    const float bb = gb[g * CPG + cw] - mean * aa;

    __shared__ float tile[CPG][260];
    for (int chunk = 0; chunk < 2; chunk++) {
        const int n0 = sl * 512 + chunk * 256;
        for (int i = tid; i < (CPG * 256) / 4; i += 256) {
            int c  = i >> 6;
            int n4 = i & 63;
            float4 v = *(const float4*)(xp + (size_t)c * NN + n0 + n4 * 4);
            tile[c][n4 * 4 + 0] = v.x;
            tile[c][n4 * 4 + 1] = v.y;
            tile[c][n4 * 4 + 2] = v.z;
            tile[c][n4 * 4 + 3] = v.w;
        }
        __syncthreads();
#pragma unroll
        for (int j = 0; j < 16; j++) {
            int n = (tid >> 4) + 16 * j;
            float v = tile[cw][n] * aa + bb;
            h[(size_t)(n0 + n) * CC + g * CPG + cw] = (bf16_t)v;
        }
        __syncthreads();
    }
}

// ---------------------------------------------------------------------------
// bf16 MFMA GEMM core: D[m][n] = scale * sum_k A[m][k] * B[n][k]
// 128x128 tile, BK=32, 4 waves (2x2), 4x4 frags of 16x16x32 (verified maps).
// MODE 0: direct bf16  out[m*ldo + n]  (+fp32 bias[n])
// MODE 2: T-store FP32 out[n*ldo + m]  + fp32 bias[n] + fp32 resid[n*ldo+m]
// ---------------------------------------------------------------------------
template <int MODE>
__global__ __launch_bounds__(256) void gemm_bt(
    const bf16_t* __restrict__ A, const bf16_t* __restrict__ B,
    void* __restrict__ Og, const float* __restrict__ bias,
    const float* __restrict__ resid, float scale,
    int K, int lda, int ldb, int ldo)
{
    __shared__ bf16_t Asm[128][40];
    __shared__ bf16_t Bsm[128][40];
    const int tid  = threadIdx.x;
    const int lane = tid & 63, wave = tid >> 6;
    const int wm = (wave >> 1) << 6, wn = (wave & 1) << 6;
    const int fr = lane & 15, fq = lane >> 4;
    const size_t m0 = (size_t)blockIdx.x * 128, n0 = (size_t)blockIdx.y * 128;
    const int r  = tid >> 2;
    const int c8 = (tid & 3) << 3;

    f4v acc[4][4];
#pragma unroll
    for (int i = 0; i < 4; i++)
#pragma unroll
        for (int j = 0; j < 4; j++) acc[i][j] = (f4v){0.f, 0.f, 0.f, 0.f};

    for (int kt = 0; kt < K; kt += 32) {
        const bf16_t* pa = A + (m0 + r) * lda + kt + c8;
        const bf16_t* pb = B + (n0 + r) * ldb + kt + c8;
        uint4 a0 = *(const uint4*)(pa);
        uint4 a1 = *(const uint4*)(pa + (size_t)64 * lda);
        uint4 b0 = *(const uint4*)(pb);
        uint4 b1 = *(const uint4*)(pb + (size_t)64 * ldb);
        __syncthreads();
        *(uint4*)&Asm[r][c8]      = a0;
        *(uint4*)&Asm[r + 64][c8] = a1;
        *(uint4*)&Bsm[r][c8]      = b0;
        *(uint4*)&Bsm[r + 64][c8] = b1;
        __syncthreads();
        bf8v af[4], bfv[4];
#pragma unroll
        for (int j = 0; j < 4; j++)
            bfv[j] = *(const bf8v*)&Bsm[wn + j * 16 + fr][fq * 8];
#pragma unroll
        for (int i = 0; i < 4; i++)
            af[i] = *(const bf8v*)&Asm[wm + i * 16 + fr][fq * 8];
#pragma unroll
        for (int i = 0; i < 4; i++)
#pragma unroll
            for (int j = 0; j < 4; j++)
                acc[i][j] = __builtin_amdgcn_mfma_f32_16x16x32_bf16(
                    af[i], bfv[j], acc[i][j], 0, 0, 0);
    }

    if (MODE == 0) {
        bf16_t* out = (bf16_t*)Og;
#pragma unroll
        for (int i = 0; i < 4; i++) {
            const int mb = (int)m0 + wm + i * 16 + fq * 4;
#pragma unroll
            for (int j = 0; j < 4; j++) {
                const int n = (int)n0 + wn + j * 16 + fr;
                const float bn = bias ? bias[n] : 0.f;
#pragma unroll
                for (int t = 0; t < 4; t++)
                    out[(size_t)(mb + t) * ldo + n] =
                        (bf16_t)(acc[i][j][t] * scale + bn);
            }
        }
    } else {
        float* out = (float*)Og;
#pragma unroll
        for (int i = 0; i < 4; i++) {
            const int mb = (int)m0 + wm + i * 16 + fq * 4;
#pragma unroll
            for (int j = 0; j < 4; j++) {
                const int n = (int)n0 + wn + j * 16 + fr;
                const float bn = bias[n];
                float4 rq = *(const float4*)(resid + (size_t)n * ldo + mb);
                float4 o4;
                o4.x = acc[i][j][0] * scale + bn + rq.x;
                o4.y = acc[i][j][1] * scale + bn + rq.y;
                o4.z = acc[i][j][2] * scale + bn + rq.z;
                o4.w = acc[i][j][3] * scale + bn + rq.w;
                *(float4*)(out + (size_t)n * ldo + mb) = o4;
            }
        }
    }
}

// ---------------------------------------------------------------------------
// Fused q/k/v GEMM: blockIdx.z selects weight/bias/output.
// z=0,1 (q,k): direct bf16 out[m*512+n]; z=2 (v): T-store bf16 out[n*4096+m].
// ---------------------------------------------------------------------------
__global__ __launch_bounds__(256) void gemm_qkv(
    const bf16_t* __restrict__ h, const bf16_t* __restrict__ Wb,
    const float* __restrict__ bq, const float* __restrict__ bk,
    const float* __restrict__ bv,
    bf16_t* __restrict__ q, bf16_t* __restrict__ k, bf16_t* __restrict__ v)
{
    __shared__ bf16_t Asm[128][40];
    __shared__ bf16_t Bsm[128][40];
    const int z = blockIdx.z;
    const bf16_t* B = Wb + (size_t)z * WSZ;
    const float* bias = (z == 0) ? bq : (z == 1) ? bk : bv;
    bf16_t* out = (z == 0) ? q : (z == 1) ? k : v;

    const int tid  = threadIdx.x;
    const int lane = tid & 63, wave = tid >> 6;
    const int wm = (wave >> 1) << 6, wn = (wave & 1) << 6;
    const int fr = lane & 15, fq = lane >> 4;
    const size_t m0 = (size_t)blockIdx.x * 128, n0 = (size_t)blockIdx.y * 128;
    const int r  = tid >> 2;
    const int c8 = (tid & 3) << 3;

    f4v acc[4][4];
#pragma unroll
    for (int i = 0; i < 4; i++)
#pragma unroll
        for (int j = 0; j < 4; j++) acc[i][j] = (f4v){0.f, 0.f, 0.f, 0.f};

    for (int kt = 0; kt < 512; kt += 32) {
        const bf16_t* pa = h + (m0 + r) * 512 + kt + c8;
        const bf16_t* pb = B + (n0 + r) * 512 + kt + c8;
        uint4 a0 = *(const uint4*)(pa);
        uint4 a1 = *(const uint4*)(pa + (size_t)64 * 512);
        uint4 b0 = *(const uint4*)(pb);
        uint4 b1 = *(const uint4*)(pb + (size_t)64 * 512);
        __syncthreads();
        *(uint4*)&Asm[r][c8]      = a0;
        *(uint4*)&Asm[r + 64][c8] = a1;
        *(uint4*)&Bsm[r][c8]      = b0;
        *(uint4*)&Bsm[r + 64][c8] = b1;
        __syncthreads();
        bf8v af[4], bfv[4];
#pragma unroll
        for (int j = 0; j < 4; j++)
            bfv[j] = *(const bf8v*)&Bsm[wn + j * 16 + fr][fq * 8];
#pragma unroll
        for (int i = 0; i < 4; i++)
            af[i] = *(const bf8v*)&Asm[wm + i * 16 + fr][fq * 8];
#pragma unroll
        for (int i = 0; i < 4; i++)
#pragma unroll
            for (int j = 0; j < 4; j++)
                acc[i][j] = __builtin_amdgcn_mfma_f32_16x16x32_bf16(
                    af[i], bfv[j], acc[i][j], 0, 0, 0);
    }

    if (z < 2) {
#pragma unroll
        for (int i = 0; i < 4; i++) {
            const int mb = (int)m0 + wm + i * 16 + fq * 4;
#pragma unroll
            for (int j = 0; j < 4; j++) {
                const int n = (int)n0 + wn + j * 16 + fr;
                const float bn = bias[n];
#pragma unroll
                for (int t = 0; t < 4; t++)
                    out[(size_t)(mb + t) * 512 + n] =
                        (bf16_t)(acc[i][j][t] + bn);
            }
        }
    } else {
#pragma unroll
        for (int i = 0; i < 4; i++) {
            const int mb = (int)m0 + wm + i * 16 + fq * 4;
#pragma unroll
            for (int j = 0; j < 4; j++) {
                const int n = (int)n0 + wn + j * 16 + fr;
                const float bn = bias[n];
                bf4v pk;
#pragma unroll
                for (int t = 0; t < 4; t++)
                    pk[t] = (bf16_t)(acc[i][j][t] + bn);
                *(bf4v*)(out + (size_t)n * NN + mb) = pk;
            }
        }
    }
}

// ---------------------------------------------------------------------------
// Row softmax over S (CH x 4096 bf16), in place. 1 wave per row.
// ---------------------------------------------------------------------------
__global__ __launch_bounds__(256) void softmax_kernel(bf16_t* __restrict__ S)
{
    const int wave = threadIdx.x >> 6, lane = threadIdx.x & 63;
    const size_t row = (size_t)blockIdx.x * 4 + wave;
    bf16_t* p = S + row * NN;
    float f[64];
    float mx = -1e30f;
#pragma unroll
    for (int c = 0; c < 8; c++) {
        bf8v v = ((const bf8v*)p)[c * 64 + lane];
#pragma unroll
        for (int j = 0; j < 8; j++) {
            f[c * 8 + j] = (float)v[j];
            mx = fmaxf(mx, f[c * 8 + j]);
        }
    }
#pragma unroll
    for (int off = 32; off > 0; off >>= 1) mx = fmaxf(mx, __shfl_xor(mx, off));
    float sum = 0.f;
#pragma unroll
    for (int i = 0; i < 64; i++) { f[i] = expf(f[i] - mx); sum += f[i]; }
#pragma unroll
    for (int off = 32; off > 0; off >>= 1) sum += __shfl_xor(sum, off);
    const float inv = 1.f / sum;
#pragma unroll
    for (int c = 0; c < 8; c++) {
        bf8v o;
#pragma unroll
        for (int j = 0; j < 8; j++) o[j] = (bf16_t)(f[c * 8 + j] * inv);
        ((bf8v*)p)[c * 64 + lane] = o;
    }
}

// ---------------------------------------------------------------------------
extern "C" void kernel_launch(void* const* d_in, const int* in_sizes, int n_in,
                              void* d_out, int out_size, void* d_ws, size_t ws_size,
                              hipStream_t stream)
{
    const float* x  = (const float*)d_in[0];
    const float* gw = (const float*)d_in[1];
    const float* gb = (const float*)d_in[2];
    const float* Wq = (const float*)d_in[3];
    const float* bq = (const float*)d_in[4];
    const float* Wk = (const float*)d_in[5];
    const float* bk = (const float*)d_in[6];
    const float* Wv = (const float*)d_in[7];
    const float* bv = (const float*)d_in[8];
    const float* Wo = (const float*)d_in[9];
    const float* bo = (const float*)d_in[10];
    float* out = (float*)d_out;          // *** fp32 output ***

    bool ok = (n_in == 11) && (out_size == BB * CC * NN) &&
              (in_sizes[0] == BB * CC * NN) &&
              (in_sizes[1] == CC) && (in_sizes[2] == CC) &&
              (in_sizes[3] == WSZ) && (in_sizes[4] == CC) &&
              (in_sizes[5] == WSZ) && (in_sizes[6] == CC) &&
              (in_sizes[7] == WSZ) && (in_sizes[8] == CC) &&
              (in_sizes[9] == WSZ) && (in_sizes[10] == CC);
    if (!ok) { diag_out<<<dim3(1), 64, 0, stream>>>(out, FLG_SIZES); return; }

    // ---- workspace (~19 MB fixed + S chunk <= 32 MB) ----
    bf16_t* Wb    = (bf16_t*)d_ws;                    // 4*WSZ bf16
    float*  stats = (float*)(Wb + (size_t)4 * WSZ);   // 512 (pad 1024)
    bf16_t* h = (bf16_t*)(stats + 1024);              // per-batch (N,C)
    bf16_t* q = h + (size_t)NCb;
    bf16_t* k = q + (size_t)NCb;
    bf16_t* v = k + (size_t)NCb;                      // (C,N)
    bf16_t* S = v + (size_t)NCb;                      // CH x 4096 bf16
    bf16_t* O = h;                                    // overlay: h dead after qkv
    const size_t fixed = (size_t)4 * WSZ * 2 + 1024 * 4 + (size_t)4 * NCb * 2;

    if (ws_size < fixed + (size_t)128 * NN * 2) {
        diag_out<<<dim3(1), 64, 0, stream>>>(out, FLG_WS); return;
    }
    int CH = 128;
    while (CH < NN && fixed + (size_t)(CH * 2) * NN * 2 <= ws_size) CH *= 2;

    cvt_w<<<dim3(256), 256, 0, stream>>>(Wq, Wk, Wv, Wo, Wb);
    gn_stats<<<dim3(256), 256, 0, stream>>>(x, stats);

    const float sc = 0.044194173824159216f;           // 512^-0.5
    for (int b = 0; b < BB; b++) {
        const float* xb   = x   + (size_t)b * CC * NN;
        float*       outb = out + (size_t)b * CC * NN;

        gn_apply<<<dim3(256), 256, 0, stream>>>(xb, gw, gb, stats, h, b * 32);
        gemm_qkv<<<dim3(32, 4, 3), 256, 0, stream>>>(h, Wb, bq, bk, bv, q, k, v);

        for (int r0 = 0; r0 < NN; r0 += CH) {
            // S[m][nk] = sc * q[r0+m] . k[nk]
            gemm_bt<0><<<dim3(CH / 128, 32), 256, 0, stream>>>(
                q + (size_t)r0 * CC, k, S, nullptr, nullptr, sc,
                512, 512, 512, 4096);
            softmax_kernel<<<dim3(CH / 4), 256, 0, stream>>>(S);
            // O[r0+m][c] = P[m] . v[c]
            gemm_bt<0><<<dim3(CH / 128, 4), 256, 0, stream>>>(
                S, v, O + (size_t)r0 * CC, nullptr, nullptr, 1.f,
                4096, 4096, 4096, 512);
        }

        // out[o][n] = O[n] . Wo[o] + bo[o] + x[o][n]   (fp32 store)
        gemm_bt<2><<<dim3(32, 4), 256, 0, stream>>>(
            O, Wb + (size_t)3 * WSZ, outb, bo, xb, 1.f,
            512, 512, 512, 4096);
    }
}